// Round 23
// baseline (73.907 us; speedup 1.0000x reference)
//
#include <hip/hip_runtime.h>

#define HD 257
#define WD 257
#define NB (8 * HD)    // 2056 (b,y)-row buckets
#define NCHUNK 32      // chunks per batch
#define CAPC 32        // per-(bucket,chunk) slot capacity (lambda~4 -> safe)
#define BPTS 1024      // bin: points per block
#define COUT 64
#define LROW 17        // accum LDS row stride (floats): breaks x*16 bank pattern
#define GPTS 64        // gather: points per tile
#define TPB 2          // gather: tiles per block

typedef unsigned int uint;
typedef unsigned short ushort;
typedef short short8 __attribute__((ext_vector_type(8)));
typedef float f32x4 __attribute__((ext_vector_type(4)));

// f32 -> bf16 RNE
__device__ __forceinline__ uint pack_bf16(float a, float b) {
    uint ua = __float_as_uint(a), ub = __float_as_uint(b);
    ua += 0x7fffu + ((ua >> 16) & 1u);
    ub += 0x7fffu + ((ub >> 16) & 1u);
    return (ua >> 16) | (ub & 0xffff0000u);
}

// K0: precompute W fragments: Wb[(s*4+hi)*64+col] = 8 bf16, elem j =
// W[(s*32+hi*8+j)*64+col], zero for k>=144. 1280 entries, ~2 us.
__global__ void wprep_kernel(const float* __restrict__ W, uint4* __restrict__ Wb) {
    int idx = blockIdx.x * blockDim.x + threadIdx.x;
    if (idx >= 5 * 4 * 64) return;
    int s = idx >> 8;
    int hi = (idx >> 6) & 3;
    int col = idx & 63;
    uint o[4];
#pragma unroll
    for (int jj = 0; jj < 4; ++jj) {
        int k0 = s * 32 + hi * 8 + 2 * jj;
        float fl = (k0 < 144) ? W[(size_t)k0 * 64 + col] : 0.0f;
        float fh = (k0 + 1 < 144) ? W[(size_t)(k0 + 1) * 64 + col] : 0.0f;
        o[jj] = pack_bf16(fl, fh);
    }
    Wb[idx] = make_uint4(o[0], o[1], o[2], o[3]);
}

// K1: bin — NO global atomics. Block (chunk,b): LDS histogram of its 1024
// points, chunk-local ranks, plain stores. Entry carries (x<<16|lp, w_bits)
// so accum never touches xyzp.
__global__ __launch_bounds__(256) void bin_kernel(
    const float* __restrict__ xyzp,
    uint* __restrict__ cnt2,     // [NB][NCHUNK]
    uint2* __restrict__ pidx2,   // [NB][NCHUNK][CAPC] {(x<<16)|lp, w_bits}
    int N) {
    __shared__ uint hist[HD];
    const int tid = threadIdx.x;
    const int chunk = blockIdx.x;
    const int b = blockIdx.y;
    const int p0 = chunk * BPTS;
    for (int i = tid; i < HD; i += 256) hist[i] = 0u;
    __syncthreads();

    const float4* xp = reinterpret_cast<const float4*>(xyzp) + (size_t)b * N;
    uint rec[BPTS / 256], xrec[BPTS / 256], wrec[BPTS / 256];
#pragma unroll
    for (int k = 0; k < BPTS / 256; ++k) {
        int i = p0 + tid + k * 256;
        float4 v = xp[i];
        int y = (int)fminf(fmaxf(rintf(v.y * 256.0f), 0.0f), 256.0f);
        int x = (int)fminf(fmaxf(rintf(v.x * 256.0f), 0.0f), 256.0f);
        uint r = atomicAdd(&hist[y], 1u);   // LDS only
        rec[k] = (uint)y | (r << 9);
        xrec[k] = (uint)x;
        wrec[k] = __float_as_uint(v.w);
    }
    __syncthreads();

    for (int y = tid; y < HD; y += 256)
        cnt2[(size_t)(b * HD + y) * NCHUNK + chunk] = min(hist[y], (uint)CAPC);

#pragma unroll
    for (int k = 0; k < BPTS / 256; ++k) {
        int y = rec[k] & 511;
        uint r = rec[k] >> 9;
        if (r < CAPC)
            pidx2[((size_t)(b * HD + y) * NCHUNK + chunk) * CAPC + r] =
                make_uint2((xrec[k] << 16) | (uint)(p0 + tid + k * 256), wrec[k]);
    }
}

// K2: accum-v6 — one bucket/block (17.5 KB LDS -> 8 blocks/CU). 2-slot batches:
// coalesced unconditional uint2 loads, then BOTH points' feat loads issued with
// clamped addresses (uniform flow, 2x MLP), then LDS atomics. No xyzp hop.
__global__ __launch_bounds__(256) void accum_kernel(
    const uint* __restrict__ cnt2,
    const uint2* __restrict__ pidx2,
    const float* __restrict__ feat,
    uint* __restrict__ voxn,       // [S][8] normalized bf16 pairs
    int logN) {
    __shared__ float l[WD * LROW];   // 17476 B
    __shared__ uint pc[NCHUNK];
    const int tid = threadIdx.x;
    const int bucket = blockIdx.x;
    const int b = bucket / HD;       // const-div -> magic mul
    for (int i = tid; i < WD * LROW; i += 256) l[i] = 0.0f;
    if (tid < NCHUNK)
        pc[tid] = cnt2[(size_t)bucket * NCHUNK + tid];
    __syncthreads();

    const uint2* base = pidx2 + (size_t)bucket * NCHUNK * CAPC;
#pragma unroll
    for (int half = 0; half < 2; ++half) {
        uint2 e[2];
        bool ok[2];
#pragma unroll
        for (int r = 0; r < 2; ++r) {
            int slot = (half * 2 + r) * 256 + tid;
            int c = slot >> 5;              // CAPC=32
            int j = slot & (CAPC - 1);
            ok[r] = (uint)j < pc[c];
            e[r] = base[slot];              // coalesced, unconditional
        }
        float2 f[2][7];
#pragma unroll
        for (int r = 0; r < 2; ++r) {
            int p = ok[r] ? ((b << logN) + (int)(e[r].x & 0xffffu)) : 0;
            const float2* f2 = reinterpret_cast<const float2*>(feat + (size_t)p * 14);
#pragma unroll
            for (int j = 0; j < 7; ++j) f[r][j] = f2[j];   // both points in flight
        }
#pragma unroll
        for (int r = 0; r < 2; ++r) {
            if (ok[r]) {
                int x = (int)(e[r].x >> 16);
                float wv = __uint_as_float(e[r].y);
                float* cell = l + x * LROW;
                atomicAdd(&cell[0], wv);
                atomicAdd(&cell[1], 1.0f - wv);
#pragma unroll
                for (int j = 0; j < 7; ++j) {
                    atomicAdd(&cell[2 + 2 * j], f[r][j].x);
                    atomicAdd(&cell[3 + 2 * j], f[r][j].y);
                }
            }
        }
    }
    __syncthreads();

    for (int x = tid; x < WD; x += 256) {
        const float* c = l + x * LROW;
        float inv = __builtin_amdgcn_rcpf(fmaxf(c[0] + c[1], 1.0f));
        uint o[8];
#pragma unroll
        for (int j = 0; j < 8; ++j)
            o[j] = pack_bf16(c[2 * j] * inv, c[2 * j + 1] * inv);
        uint4* op = reinterpret_cast<uint4*>(voxn + ((size_t)bucket * WD + x) * 8);
        op[0] = make_uint4(o[0], o[1], o[2], o[3]);
        op[1] = make_uint4(o[4], o[5], o[6], o[7]);
    }
}

// K3: gather-v7 — TPB tiles per block; B-frags/bias/zero-pad hoisted (paid
// once per block); B-frags are 5 coalesced 16 B loads from precomputed Wb.
// Per tile: point-data, A-build, MFMA, NT store — identical math to v3.
__global__ __launch_bounds__(256) void gather_mfma_kernel(
    const float* __restrict__ xyzp,
    const uint* __restrict__ voxn,   // [S][8] normalized bf16 pairs
    const uint4* __restrict__ Wb,    // precomputed bf16 B-fragments
    const float* __restrict__ bias,
    float* __restrict__ out, int logN) {
    __shared__ __align__(16) char sA[GPTS * 336];  // 21504 B -> 7 blocks/CU
    __shared__ int sCell[GPTS];
    __shared__ uint sYX[GPTS];

    const int tid = threadIdx.x;
    const int lane = tid & 63;
    const int w = tid >> 6;
    const int hi = lane >> 4;
    const int lo = lane & 15;

    // hoisted: B fragments (5 coalesced 16B loads) + bias
    short8 bfrag[5];
    float bv = bias[w * 16 + lo];
    {
        const uint4* wb = Wb + hi * 64 + (w * 16 + lo);
#pragma unroll
        for (int s = 0; s < 5; ++s)
            bfrag[s] = *reinterpret_cast<const short8*>(&wb[(size_t)s * 256]);
    }
    // hoisted: zero-pad k in [144,160) — A-build never writes bytes 288..335
    if (tid < GPTS * 2) {
        int i = tid >> 1, h = tid & 1;
        *reinterpret_cast<uint4*>(sA + i * 336 + 288 + h * 16) = make_uint4(0, 0, 0, 0);
    }

#pragma unroll
    for (int t = 0; t < TPB; ++t) {
        const int p0 = (blockIdx.x * TPB + t) * GPTS;
        __syncthreads();   // prev tile's MFMA/A-reads done before LDS rewrite
        if (tid < GPTS) {
            float4 v = reinterpret_cast<const float4*>(xyzp)[p0 + tid];
            int y = (int)fminf(fmaxf(rintf(v.y * 256.0f), 0.0f), 256.0f);
            int x = (int)fminf(fmaxf(rintf(v.x * 256.0f), 0.0f), 256.0f);
            int b = (p0 + tid) >> logN;
            sCell[tid] = (b * HD + y) * WD + x;
            sYX[tid] = ((uint)y << 16) | (uint)x;
        }
        __syncthreads();

        // A build: 18 chunks/point (3 dy-segs x 3 kx x 2 halves of 16 B)
        for (int idx = tid; idx < GPTS * 18; idx += 256) {
            int i = idx / 18;
            int r = idx - i * 18;
            int seg = r / 6;          // dy+1
            int h = r - seg * 6;
            int kx = h >> 1;
            int half = h & 1;
            uint yx = sYX[i];
            int y = (int)(yx >> 16), x = (int)(yx & 0xffffu);
            int ny = y + seg - 1, nx = x + kx - 1;
            uint4 val = make_uint4(0, 0, 0, 0);
            if ((uint)ny <= 256u && (uint)nx <= 256u) {
                size_t ncell = (size_t)sCell[i] + (size_t)((seg - 1) * WD + (kx - 1));
                val = *reinterpret_cast<const uint4*>(
                    reinterpret_cast<const char*>(voxn) + ncell * 32 + (size_t)half * 16);
            }
            *reinterpret_cast<uint4*>(sA + i * 336 + (seg * 3 + kx) * 32 + half * 16) = val;
        }
        __syncthreads();

        f32x4 acc[4];
#pragma unroll
        for (int mt = 0; mt < 4; ++mt) acc[mt] = (f32x4){bv, bv, bv, bv};

#pragma unroll
        for (int mt = 0; mt < 4; ++mt) {
            const char* abase = sA + (mt * 16 + lo) * 336 + hi * 16;
#pragma unroll
            for (int s = 0; s < 5; ++s) {
                short8 a = *reinterpret_cast<const short8*>(abase + s * 64);
                acc[mt] = __builtin_amdgcn_mfma_f32_16x16x32_bf16(a, bfrag[s], acc[mt], 0, 0, 0);
            }
        }

        // store: D col = lane&15, row = hi*4 + reg (m89-verified); non-temporal
#pragma unroll
        for (int mt = 0; mt < 4; ++mt)
#pragma unroll
            for (int r = 0; r < 4; ++r) {
                int row = mt * 16 + hi * 4 + r;
                __builtin_nontemporal_store(acc[mt][r],
                                            &out[(size_t)(p0 + row) * 64 + w * 16 + lo]);
            }
    }
}

extern "C" void kernel_launch(void* const* d_in, const int* in_sizes, int n_in,
                              void* d_out, int out_size, void* d_ws, size_t ws_size,
                              hipStream_t stream) {
    const float* xyzp = (const float*)d_in[0];
    const float* feat = (const float*)d_in[1];
    const float* W    = (const float*)d_in[2];
    const float* bias = (const float*)d_in[3];
    float* out = (float*)d_out;

    const int BN = in_sizes[0] / 4;  // 262144
    const int B = 8;
    const int N = BN / B;            // 32768
    int logN = 0;
    while ((1 << logN) < N) ++logN;  // 15

    // ws layout: cnt2 | pidx2 | voxn | Wb  ~= 25.6 MB
    uint* cnt2 = (uint*)d_ws;                                        // NB*32*4 = 263168 B
    uint2* pidx2 = (uint2*)((char*)cnt2 + (size_t)NB * NCHUNK * 4);  // NB*32*32*8 = 8.42 MB
    uint* voxn = (uint*)((char*)pidx2 + (size_t)NB * NCHUNK * CAPC * 8);  // 16.9 MB
    uint4* Wb = (uint4*)((char*)voxn + (size_t)(8 * HD * WD) * 32);  // 20480 B
    (void)ws_size;

    wprep_kernel<<<5, 256, 0, stream>>>(W, Wb);
    dim3 bgrid(NCHUNK, B);           // 32 x 8
    bin_kernel<<<bgrid, 256, 0, stream>>>(xyzp, cnt2, pidx2, N);
    accum_kernel<<<NB, 256, 0, stream>>>(cnt2, pidx2, feat, voxn, logN);
    gather_mfma_kernel<<<BN / (GPTS * TPB), 256, 0, stream>>>(xyzp, voxn, Wb, bias, out, logN);
}

// Round 24
// 66.054 us; speedup vs baseline: 1.1189x; 1.1189x over previous
//
#include <hip/hip_runtime.h>

#define HD 257
#define WD 257
#define NB (8 * HD)    // 2056 (b,y)-row buckets
#define NCHUNK 32      // chunks per batch
#define CAPC 32        // per-(bucket,chunk) slot capacity (lambda~4 -> safe)
#define BPTS 1024      // bin: points per block
#define COUT 64
#define LROW 17        // accum LDS row stride (floats): breaks x*16 bank pattern
#define GPTS 64        // gather: points per block

typedef unsigned int uint;
typedef unsigned short ushort;
typedef short short8 __attribute__((ext_vector_type(8)));
typedef float f32x4 __attribute__((ext_vector_type(4)));

// f32 -> bf16 RNE
__device__ __forceinline__ uint pack_bf16(float a, float b) {
    uint ua = __float_as_uint(a), ub = __float_as_uint(b);
    ua += 0x7fffu + ((ua >> 16) & 1u);
    ub += 0x7fffu + ((ub >> 16) & 1u);
    return (ua >> 16) | (ub & 0xffff0000u);
}
__device__ __forceinline__ unsigned short bf16_1(float a) {
    uint ua = __float_as_uint(a);
    ua += 0x7fffu + ((ua >> 16) & 1u);
    return (unsigned short)(ua >> 16);
}

// K1: bin — NO global atomics. Block (chunk,b): LDS histogram of its 1024
// points, chunk-local ranks, plain stores. Entry carries (x<<16|lp, w_bits)
// so accum never touches xyzp (one dependent hop shorter).
__global__ __launch_bounds__(256) void bin_kernel(
    const float* __restrict__ xyzp,
    uint* __restrict__ cnt2,     // [NB][NCHUNK]
    uint2* __restrict__ pidx2,   // [NB][NCHUNK][CAPC] {(x<<16)|lp, w_bits}
    int N) {
    __shared__ uint hist[HD];
    const int tid = threadIdx.x;
    const int chunk = blockIdx.x;
    const int b = blockIdx.y;
    const int p0 = chunk * BPTS;
    for (int i = tid; i < HD; i += 256) hist[i] = 0u;
    __syncthreads();

    const float4* xp = reinterpret_cast<const float4*>(xyzp) + (size_t)b * N;
    uint rec[BPTS / 256], xrec[BPTS / 256], wrec[BPTS / 256];
#pragma unroll
    for (int k = 0; k < BPTS / 256; ++k) {
        int i = p0 + tid + k * 256;
        float4 v = xp[i];
        int y = (int)fminf(fmaxf(rintf(v.y * 256.0f), 0.0f), 256.0f);
        int x = (int)fminf(fmaxf(rintf(v.x * 256.0f), 0.0f), 256.0f);
        uint r = atomicAdd(&hist[y], 1u);   // LDS only
        rec[k] = (uint)y | (r << 9);
        xrec[k] = (uint)x;
        wrec[k] = __float_as_uint(v.w);
    }
    __syncthreads();

    for (int y = tid; y < HD; y += 256)
        cnt2[(size_t)(b * HD + y) * NCHUNK + chunk] = min(hist[y], (uint)CAPC);

#pragma unroll
    for (int k = 0; k < BPTS / 256; ++k) {
        int y = rec[k] & 511;
        uint r = rec[k] >> 9;
        if (r < CAPC)
            pidx2[((size_t)(b * HD + y) * NCHUNK + chunk) * CAPC + r] =
                make_uint2((xrec[k] << 16) | (uint)(p0 + tid + k * 256), wrec[k]);
    }
}

// K2: accum-v6 — one bucket/block (17.5 KB LDS -> 8 blocks/CU). 2-slot batches:
// coalesced unconditional uint2 loads, then BOTH points' feat loads issued with
// clamped addresses (uniform flow, 2x MLP), then LDS atomics. No xyzp hop.
__global__ __launch_bounds__(256) void accum_kernel(
    const uint* __restrict__ cnt2,
    const uint2* __restrict__ pidx2,
    const float* __restrict__ feat,
    uint* __restrict__ voxn,       // [S][8] normalized bf16 pairs
    int logN) {
    __shared__ float l[WD * LROW];   // 17476 B
    __shared__ uint pc[NCHUNK];
    const int tid = threadIdx.x;
    const int bucket = blockIdx.x;
    const int b = bucket / HD;       // const-div -> magic mul
    for (int i = tid; i < WD * LROW; i += 256) l[i] = 0.0f;
    if (tid < NCHUNK)
        pc[tid] = cnt2[(size_t)bucket * NCHUNK + tid];
    __syncthreads();

    const uint2* base = pidx2 + (size_t)bucket * NCHUNK * CAPC;
#pragma unroll
    for (int half = 0; half < 2; ++half) {
        uint2 e[2];
        bool ok[2];
#pragma unroll
        for (int r = 0; r < 2; ++r) {
            int slot = (half * 2 + r) * 256 + tid;
            int c = slot >> 5;              // CAPC=32
            int j = slot & (CAPC - 1);
            ok[r] = (uint)j < pc[c];
            e[r] = base[slot];              // coalesced, unconditional
        }
        float2 f[2][7];
#pragma unroll
        for (int r = 0; r < 2; ++r) {
            int p = ok[r] ? ((b << logN) + (int)(e[r].x & 0xffffu)) : 0;
            const float2* f2 = reinterpret_cast<const float2*>(feat + (size_t)p * 14);
#pragma unroll
            for (int j = 0; j < 7; ++j) f[r][j] = f2[j];   // both points in flight
        }
#pragma unroll
        for (int r = 0; r < 2; ++r) {
            if (ok[r]) {
                int x = (int)(e[r].x >> 16);
                float wv = __uint_as_float(e[r].y);
                float* cell = l + x * LROW;
                atomicAdd(&cell[0], wv);
                atomicAdd(&cell[1], 1.0f - wv);
#pragma unroll
                for (int j = 0; j < 7; ++j) {
                    atomicAdd(&cell[2 + 2 * j], f[r][j].x);
                    atomicAdd(&cell[3 + 2 * j], f[r][j].y);
                }
            }
        }
    }
    __syncthreads();

    for (int x = tid; x < WD; x += 256) {
        const float* c = l + x * LROW;
        float inv = __builtin_amdgcn_rcpf(fmaxf(c[0] + c[1], 1.0f));
        uint o[8];
#pragma unroll
        for (int j = 0; j < 8; ++j)
            o[j] = pack_bf16(c[2 * j] * inv, c[2 * j + 1] * inv);
        uint4* op = reinterpret_cast<uint4*>(voxn + ((size_t)bucket * WD + x) * 8);
        op[0] = make_uint4(o[0], o[1], o[2], o[3]);
        op[1] = make_uint4(o[4], o[5], o[6], o[7]);
    }
}

// K3: gather-v3: 64 points / 256 thr (4 waves). A[64][K=160] bf16 in LDS
// (336 B row). Wave w computes cols w*16..w*16+15 over all 64 rows.
// k = (dy*3+dx)*16 + c.
__global__ __launch_bounds__(256) void gather_mfma_kernel(
    const float* __restrict__ xyzp,
    const uint* __restrict__ voxn,   // [S][8] normalized bf16 pairs
    const float* __restrict__ W,     // [9][16][64] f32 = [144][64]
    const float* __restrict__ bias,
    float* __restrict__ out, int logN) {
    __shared__ __align__(16) char sA[GPTS * 336];  // 21504 B
    __shared__ int sCell[GPTS];
    __shared__ uint sYX[GPTS];

    const int tid = threadIdx.x;
    const int lane = tid & 63;
    const int w = tid >> 6;
    const int p0 = blockIdx.x * GPTS;
    const int hi = lane >> 4;
    const int lo = lane & 15;

    // per-point data computed ONCE (threads 0..63)
    if (tid < GPTS) {
        float4 v = reinterpret_cast<const float4*>(xyzp)[p0 + tid];
        int y = (int)fminf(fmaxf(rintf(v.y * 256.0f), 0.0f), 256.0f);
        int x = (int)fminf(fmaxf(rintf(v.x * 256.0f), 0.0f), 256.0f);
        int b = (p0 + tid) >> logN;
        sCell[tid] = (b * HD + y) * WD + x;
        sYX[tid] = ((uint)y << 16) | (uint)x;
    }

    // B fragments (issued before barrier; latency overlaps)
    short8 bfrag[5];
    float bv = bias[w * 16 + lo];
#pragma unroll
    for (int s = 0; s < 5; ++s) {
        int kbase = s * 32 + hi * 8;
        short8 f;
#pragma unroll
        for (int j = 0; j < 8; ++j) {
            int k = kbase + j;
            float wv = (k < 144) ? W[(size_t)k * 64 + w * 16 + lo] : 0.0f;
            f[j] = (short)bf16_1(wv);
        }
        bfrag[s] = f;
    }
    __syncthreads();

    // A build: 18 chunks/point (3 dy-segs x 3 kx x 2 halves of 16 B)
    for (int idx = tid; idx < GPTS * 18; idx += 256) {
        int i = idx / 18;
        int r = idx - i * 18;
        int seg = r / 6;          // dy+1
        int h = r - seg * 6;
        int kx = h >> 1;
        int half = h & 1;
        uint yx = sYX[i];
        int y = (int)(yx >> 16), x = (int)(yx & 0xffffu);
        int ny = y + seg - 1, nx = x + kx - 1;
        uint4 val = make_uint4(0, 0, 0, 0);
        if ((uint)ny <= 256u && (uint)nx <= 256u) {
            size_t ncell = (size_t)sCell[i] + (size_t)((seg - 1) * WD + (kx - 1));
            val = *reinterpret_cast<const uint4*>(
                reinterpret_cast<const char*>(voxn) + ncell * 32 + (size_t)half * 16);
        }
        *reinterpret_cast<uint4*>(sA + i * 336 + (seg * 3 + kx) * 32 + half * 16) = val;
    }
    // zero-pad k in [144,160)
    if (tid < GPTS * 2) {
        int i = tid >> 1, h = tid & 1;
        *reinterpret_cast<uint4*>(sA + i * 336 + 288 + h * 16) = make_uint4(0, 0, 0, 0);
    }
    __syncthreads();

    f32x4 acc[4];
#pragma unroll
    for (int mt = 0; mt < 4; ++mt) acc[mt] = (f32x4){bv, bv, bv, bv};

#pragma unroll
    for (int mt = 0; mt < 4; ++mt) {
        const char* abase = sA + (mt * 16 + lo) * 336 + hi * 16;
#pragma unroll
        for (int s = 0; s < 5; ++s) {
            short8 a = *reinterpret_cast<const short8*>(abase + s * 64);
            acc[mt] = __builtin_amdgcn_mfma_f32_16x16x32_bf16(a, bfrag[s], acc[mt], 0, 0, 0);
        }
    }

    // store: D col = lane&15, row = hi*4 + reg (m89-verified); non-temporal
#pragma unroll
    for (int mt = 0; mt < 4; ++mt)
#pragma unroll
        for (int r = 0; r < 4; ++r) {
            int row = mt * 16 + hi * 4 + r;
            __builtin_nontemporal_store(acc[mt][r],
                                        &out[(size_t)(p0 + row) * 64 + w * 16 + lo]);
        }
}

extern "C" void kernel_launch(void* const* d_in, const int* in_sizes, int n_in,
                              void* d_out, int out_size, void* d_ws, size_t ws_size,
                              hipStream_t stream) {
    const float* xyzp = (const float*)d_in[0];
    const float* feat = (const float*)d_in[1];
    const float* W    = (const float*)d_in[2];
    const float* bias = (const float*)d_in[3];
    float* out = (float*)d_out;

    const int BN = in_sizes[0] / 4;  // 262144
    const int B = 8;
    const int N = BN / B;            // 32768
    int logN = 0;
    while ((1 << logN) < N) ++logN;  // 15

    // ws layout: cnt2 | pidx2 | voxn  ~= 25.6 MB
    uint* cnt2 = (uint*)d_ws;                                        // NB*32*4 = 263168 B
    uint2* pidx2 = (uint2*)((char*)cnt2 + (size_t)NB * NCHUNK * 4);  // NB*32*32*8 = 8.42 MB
    uint* voxn = (uint*)((char*)pidx2 + (size_t)NB * NCHUNK * CAPC * 8);  // 16.9 MB
    (void)ws_size;

    dim3 bgrid(NCHUNK, B);           // 32 x 8
    bin_kernel<<<bgrid, 256, 0, stream>>>(xyzp, cnt2, pidx2, N);
    accum_kernel<<<NB, 256, 0, stream>>>(cnt2, pidx2, feat, voxn, logN);
    gather_mfma_kernel<<<BN / GPTS, 256, 0, stream>>>(xyzp, voxn, W, bias, out, logN);
}